// Round 3
// baseline (956.854 us; speedup 1.0000x reference)
//
#include <hip/hip_runtime.h>
#include <hip/hip_bf16.h>

// ExpertMLPsV2: T=4096, H=2048, I=4096, E=8, TOPK=2.
// route -> bf16 weight transpose -> gu GEMM (dbuf, fused silu*up*aff)
// -> dn GEMM (dbuf, dense obuf stores) -> combine (out = sum of slots).

constexpr int kT   = 4096;
constexpr int kH   = 2048;
constexpr int kI   = 4096;
constexpr int kE   = 8;
constexpr int kCap = 4096;

typedef __attribute__((ext_vector_type(8))) short bf16x8;
typedef __attribute__((ext_vector_type(4))) float f32x4;

// ---------------- workspace layout ----------------
constexpr size_t HSB_OFF   = 0;                                   // hs bf16: 16 MiB
constexpr size_t HSB_BYTES = (size_t)kT * kH * 2;
constexpr size_t HBUF_OFF  = HSB_OFF + HSB_BYTES;                 // h bf16 (2T+128) x I
constexpr size_t HBUF_BYTES = (size_t)(2 * kT + 128) * kI * 2;
constexpr size_t CNT_OFF   = HBUF_OFF + HBUF_BYTES;
constexpr size_t OFF_OFF   = CNT_OFF + 256;
constexpr size_t LTOK_OFF  = OFF_OFF + 256;
constexpr size_t LW_OFF    = LTOK_OFF + (size_t)kE * kCap * 4;
constexpr size_t POS_OFF   = LW_OFF + (size_t)kE * kCap * 4;      // (e<<12)|slot per token, 2 per token
constexpr size_t WGT_OFF   = POS_OFF + (size_t)kT * 2 * 4;        // wg^T bf16 (E,I,H) -- later aliased by obuf
constexpr size_t WMAT_B    = (size_t)kE * kH * kI * 2;            // 128 MiB each
constexpr size_t WUT_OFF   = WGT_OFF + WMAT_B;
constexpr size_t WDT_OFF   = WUT_OFF + WMAT_B;
// obuf (fp32, 8192 x kH = 64 MiB) aliases WGT_OFF: wgT is dead before dn runs,
// and is rebuilt by tcvt on every launch (graph-replay safe).

__device__ __forceinline__ unsigned short f2bf(float x) {   // RNE f32 -> bf16
  unsigned int u = __float_as_uint(x);
  u += 0x7FFFu + ((u >> 16) & 1u);
  return (unsigned short)(u >> 16);
}

__device__ __forceinline__ float silu_f(float x) { return x / (1.f + __expf(-x)); }

__device__ __forceinline__ void async_copy16(void* lds, const void* g) {
  __builtin_amdgcn_global_load_lds(
      (const __attribute__((address_space(1))) void*)g,
      (__attribute__((address_space(3))) void*)lds, 16, 0, 0);
}

// [128 rows][64 k] bf16 tile, 16B slots XOR'd with row&7 (conflict-free)
__device__ __forceinline__ bf16x8 readT64(const unsigned short* s, int row, int kk) {
  return *(const bf16x8*)((const char*)s + row * 128 + ((((kk >> 3) ^ row) & 7) << 4));
}
// [128 rows][32 k] bf16 tile, 16B slots XOR'd with row&3 (4-way residual conflict)
__device__ __forceinline__ bf16x8 readT32(const unsigned short* s, int row, int kk) {
  return *(const bf16x8*)((const char*)s + row * 64 + ((((kk >> 3) ^ row) & 3) << 4));
}

// ---------------- kernel 1: fp32 -> bf16 hidden states ----------------
__global__ void cvt_hs_kernel(const float* __restrict__ in, unsigned short* __restrict__ out) {
  size_t i = ((size_t)blockIdx.x * 256 + threadIdx.x) * 8;
  float4 a = *(const float4*)(in + i);
  float4 b = *(const float4*)(in + i + 4);
  uint4 v;
  v.x = (unsigned)f2bf(a.x) | ((unsigned)f2bf(a.y) << 16);
  v.y = (unsigned)f2bf(a.z) | ((unsigned)f2bf(a.w) << 16);
  v.z = (unsigned)f2bf(b.x) | ((unsigned)f2bf(b.y) << 16);
  v.w = (unsigned)f2bf(b.z) | ((unsigned)f2bf(b.w) << 16);
  *(uint4*)(out + i) = v;
}

// ---------------- kernel 1b: transpose+convert weights (K,N) f32 -> (N,K) bf16 ----
__global__ __launch_bounds__(256)
void tcvt_kernel(const float* __restrict__ src, unsigned short* __restrict__ dst,
                 int K, int N) {
  __shared__ __attribute__((aligned(16))) unsigned short s[64][72];
  const size_t mat = (size_t)K * N;
  const float* S = src + (size_t)blockIdx.z * mat;
  unsigned short* D = dst + (size_t)blockIdx.z * mat;
  const int k0 = blockIdx.y * 64, n0 = blockIdx.x * 64;
  const int t  = threadIdx.x;
  const int n4 = (t & 15) * 4;
  const int k4 = (t >> 4) * 4;
  const float* p0 = S + (size_t)(k0 + k4) * N + n0 + n4;
  float4 r0 = *(const float4*)(p0);
  float4 r1 = *(const float4*)(p0 + N);
  float4 r2 = *(const float4*)(p0 + 2 * (size_t)N);
  float4 r3 = *(const float4*)(p0 + 3 * (size_t)N);
  {
    uint2 v;
    v.x = (unsigned)f2bf(r0.x) | ((unsigned)f2bf(r1.x) << 16);
    v.y = (unsigned)f2bf(r2.x) | ((unsigned)f2bf(r3.x) << 16);
    *(uint2*)(&s[n4 + 0][k4]) = v;
    v.x = (unsigned)f2bf(r0.y) | ((unsigned)f2bf(r1.y) << 16);
    v.y = (unsigned)f2bf(r2.y) | ((unsigned)f2bf(r3.y) << 16);
    *(uint2*)(&s[n4 + 1][k4]) = v;
    v.x = (unsigned)f2bf(r0.z) | ((unsigned)f2bf(r1.z) << 16);
    v.y = (unsigned)f2bf(r2.z) | ((unsigned)f2bf(r3.z) << 16);
    *(uint2*)(&s[n4 + 2][k4]) = v;
    v.x = (unsigned)f2bf(r0.w) | ((unsigned)f2bf(r1.w) << 16);
    v.y = (unsigned)f2bf(r2.w) | ((unsigned)f2bf(r3.w) << 16);
    *(uint2*)(&s[n4 + 3][k4]) = v;
  }
  __syncthreads();
  const int nn = t >> 3;
  const int kc = (t & 7) * 8;
#pragma unroll
  for (int i = 0; i < 2; ++i) {
    const int n = nn + i * 32;
    uint4 v = *(const uint4*)(&s[n][kc]);
    *(uint4*)(D + (size_t)(n0 + n) * K + k0 + kc) = v;
  }
}

// ---------------- kernel 2: routing ----------------
__global__ void route_kernel(const float* __restrict__ aff, const int* __restrict__ idx,
                             int* counts, int* ltok, float* lw, int* pos) {
  int t = blockIdx.x * 256 + threadIdx.x;
  if (t >= kT) return;
  int e0 = idx[t * 2 + 0];
  int e1 = idx[t * 2 + 1];
  float a0 = aff[t * kE + e0];
  float a1 = aff[t * kE + e1];
  if (e0 == e1) {
    float w = a0 / fmaxf(fabsf(a0), 1e-12f);
    int s = atomicAdd(&counts[e0], 1);
    ltok[e0 * kCap + s] = t;
    lw[e0 * kCap + s]   = w;
    pos[t * 2 + 0] = (e0 << 12) | s;
    pos[t * 2 + 1] = -1;
  } else {
    float d = fmaxf(fabsf(a0) + fabsf(a1), 1e-12f);
    int s0 = atomicAdd(&counts[e0], 1);
    ltok[e0 * kCap + s0] = t;
    lw[e0 * kCap + s0]   = a0 / d;
    int s1 = atomicAdd(&counts[e1], 1);
    ltok[e1 * kCap + s1] = t;
    lw[e1 * kCap + s1]   = a1 / d;
    pos[t * 2 + 0] = (e0 << 12) | s0;
    pos[t * 2 + 1] = (e1 << 12) | s1;
  }
}

__global__ void prefix_kernel(const int* __restrict__ counts, int* offs) {
  if (threadIdx.x == 0 && blockIdx.x == 0) {
    int acc = 0;
    for (int e = 0; e < kE; ++e) { offs[e] = acc; acc += counts[e]; }
  }
}

// ---------------- kernel 3: gate/up GEMM, BK=32, double-buffered ----------------
// grid (I/128, kCap/128, E), 256 threads.
__global__ __launch_bounds__(256, 2)
void gemm_gu_kernel(const unsigned short* __restrict__ hsb,
                    const unsigned short* __restrict__ wgT,   // (E, I, H) bf16
                    const unsigned short* __restrict__ wuT,
                    const int* __restrict__ counts, const int* __restrict__ offs,
                    const int* __restrict__ ltok, const float* __restrict__ lw,
                    unsigned short* __restrict__ hbuf) {
  __shared__ __attribute__((aligned(16))) unsigned short sWg[2][128 * 32];
  __shared__ __attribute__((aligned(16))) unsigned short sWu[2][128 * 32];
  __shared__ __attribute__((aligned(16))) unsigned short sAct[2][128 * 32];
  __shared__ float sWt[128];

  const int e   = blockIdx.z;
  const int cnt = counts[e];
  const int m0  = blockIdx.y * 128;
  if (m0 >= cnt) return;
  const int n0   = blockIdx.x * 128;
  const int tid  = threadIdx.x;
  const int lane = tid & 63;
  const int wv   = tid >> 6;
  const int wn   = wv & 1;
  const int wm   = wv >> 1;

  if (tid < 128) {
    int s = m0 + tid;
    sWt[tid] = (s < cnt) ? lw[e * kCap + s] : 0.f;
  }

  // per-thread gathered token rows for act staging (rows tid>>2 and 64+(tid>>2))
  const int r0 = tid >> 2;
  const int s0i = m0 + r0,      s1i = m0 + 64 + r0;
  const int tok0 = ltok[e * kCap + (s0i < cnt ? s0i : 0)];
  const int tok1 = ltok[e * kCap + (s1i < cnt ? s1i : 0)];

  const unsigned short* wg_e = wgT + (size_t)e * kI * kH;
  const unsigned short* wu_e = wuT + (size_t)e * kI * kH;

  // stage tile (BK=32): 512 chunks of 16B per tile, 2 per thread
  const int c0 = tid,        c1 = tid + 256;
  const int row0 = c0 >> 2,  row1 = c1 >> 2;
  const int kx0 = (((c0 & 3) ^ row0) & 3) << 3;   // pre-swizzled k offset (bf16 units)
  const int kx1 = (((c1 & 3) ^ row1) & 3) << 3;

#define GU_STAGE(b, k0)                                                          \
  {                                                                              \
    async_copy16((char*)sWg[b] + (size_t)c0 * 16,                                \
                 wg_e + (size_t)(n0 + row0) * kH + (k0) + kx0);                  \
    async_copy16((char*)sWg[b] + (size_t)c1 * 16,                                \
                 wg_e + (size_t)(n0 + row1) * kH + (k0) + kx1);                  \
    async_copy16((char*)sWu[b] + (size_t)c0 * 16,                                \
                 wu_e + (size_t)(n0 + row0) * kH + (k0) + kx0);                  \
    async_copy16((char*)sWu[b] + (size_t)c1 * 16,                                \
                 wu_e + (size_t)(n0 + row1) * kH + (k0) + kx1);                  \
    async_copy16((char*)sAct[b] + (size_t)c0 * 16, hsb + (size_t)tok0 * kH + (k0) + kx0); \
    async_copy16((char*)sAct[b] + (size_t)c1 * 16, hsb + (size_t)tok1 * kH + (k0) + kx1); \
  }

  f32x4 accG[4][4] = {};
  f32x4 accU[4][4] = {};

  GU_STAGE(0, 0);
  __syncthreads();

  constexpr int NK = kH / 32;   // 64
  const int kk = (lane >> 4) * 8;
  for (int kt = 0; kt < NK; ++kt) {
    const int cur = kt & 1;
    if (kt + 1 < NK) GU_STAGE(cur ^ 1, (kt + 1) * 32);
    const unsigned short* bWg = sWg[cur];
    const unsigned short* bWu = sWu[cur];
    const unsigned short* bAc = sAct[cur];
    bf16x8 aG[4], aU[4], bA[4];
#pragma unroll
    for (int i = 0; i < 4; ++i) {
      aG[i] = readT32(bWg, wn * 64 + i * 16 + (lane & 15), kk);
      aU[i] = readT32(bWu, wn * 64 + i * 16 + (lane & 15), kk);
      bA[i] = readT32(bAc, wm * 64 + i * 16 + (lane & 15), kk);
    }
#pragma unroll
    for (int i = 0; i < 4; ++i)
#pragma unroll
      for (int j = 0; j < 4; ++j) {
        accG[i][j] = __builtin_amdgcn_mfma_f32_16x16x32_bf16(aG[i], bA[j], accG[i][j], 0, 0, 0);
        accU[i][j] = __builtin_amdgcn_mfma_f32_16x16x32_bf16(aU[i], bA[j], accU[i][j], 0, 0, 0);
      }
    __syncthreads();
  }
#undef GU_STAGE

  const int lrow = (lane >> 4) * 4;
  const int lcol = lane & 15;
  const size_t rowbase = (size_t)(offs[e] + m0);
#pragma unroll
  for (int i = 0; i < 4; ++i) {
    const int ncol = n0 + wn * 64 + i * 16 + lrow;
#pragma unroll
    for (int j = 0; j < 4; ++j) {
      const int mloc = wm * 64 + j * 16 + lcol;
      if (m0 + mloc < cnt) {
        const float wgt = sWt[mloc];
        f32x4 g = accG[i][j], u = accU[i][j];
        float h0 = silu_f(g[0]) * u[0] * wgt;
        float h1 = silu_f(g[1]) * u[1] * wgt;
        float h2 = silu_f(g[2]) * u[2] * wgt;
        float h3 = silu_f(g[3]) * u[3] * wgt;
        uint2 v;
        v.x = (unsigned)f2bf(h0) | ((unsigned)f2bf(h1) << 16);
        v.y = (unsigned)f2bf(h2) | ((unsigned)f2bf(h3) << 16);
        *(uint2*)(hbuf + ((rowbase + mloc) * kI + ncol)) = v;
      }
    }
  }
}

// ---------------- kernel 4: down GEMM, BK=64, double-buffered, dense stores ----
// grid (H/128, kCap/128, E), 256 threads.
__global__ __launch_bounds__(256, 2)
void gemm_dn_kernel(const unsigned short* __restrict__ hbuf,
                    const unsigned short* __restrict__ wdT,   // (E, H, I) bf16
                    const int* __restrict__ counts, const int* __restrict__ offs,
                    float* __restrict__ obuf) {
  __shared__ __attribute__((aligned(16))) unsigned short sW[2][128 * 64];
  __shared__ __attribute__((aligned(16))) unsigned short sAct[2][128 * 64];

  const int e   = blockIdx.z;
  const int cnt = counts[e];
  const int m0  = blockIdx.y * 128;
  if (m0 >= cnt) return;
  const int n0   = blockIdx.x * 128;
  const int tid  = threadIdx.x;
  const int lane = tid & 63;
  const int wv   = tid >> 6;
  const int wn   = wv & 1;
  const int wm   = wv >> 1;
  const int base_row = offs[e] + m0;

  const unsigned short* wd_e = wdT + (size_t)e * kH * kI;
  const unsigned short* act_b = hbuf + (size_t)base_row * kI;

#define DN_STAGE(b, k0)                                                          \
  {                                                                              \
    _Pragma("unroll")                                                            \
    for (int it = 0; it < 4; ++it) {                                             \
      const int c   = it * 256 + tid;                                            \
      const int row = c >> 3;                                                    \
      const int kof = (k0) + ((((c & 7) ^ row) & 7) << 3);                       \
      async_copy16((char*)sW[b] + (size_t)c * 16,                                \
                   wd_e + (size_t)(n0 + row) * kI + kof);                        \
      async_copy16((char*)sAct[b] + (size_t)c * 16,                              \
                   act_b + (size_t)row * kI + kof);                              \
    }                                                                            \
  }

  f32x4 acc[4][4] = {};

  DN_STAGE(0, 0);
  __syncthreads();

  constexpr int NK = kI / 64;   // 64
  for (int kt = 0; kt < NK; ++kt) {
    const int cur = kt & 1;
    if (kt + 1 < NK) DN_STAGE(cur ^ 1, (kt + 1) * 64);
    const unsigned short* bW = sW[cur];
    const unsigned short* bA = sAct[cur];
#pragma unroll
    for (int kf = 0; kf < 2; ++kf) {
      const int kk = kf * 32 + (lane >> 4) * 8;
      bf16x8 aW[4], aA[4];
#pragma unroll
      for (int i = 0; i < 4; ++i) {
        aW[i] = readT64(bW, wn * 64 + i * 16 + (lane & 15), kk);
        aA[i] = readT64(bA, wm * 64 + i * 16 + (lane & 15), kk);
      }
#pragma unroll
      for (int i = 0; i < 4; ++i)
#pragma unroll
        for (int j = 0; j < 4; ++j)
          acc[i][j] = __builtin_amdgcn_mfma_f32_16x16x32_bf16(aW[i], aA[j], acc[i][j], 0, 0, 0);
    }
    __syncthreads();
  }
#undef DN_STAGE

  const int lrow = (lane >> 4) * 4;
  const int lcol = lane & 15;
#pragma unroll
  for (int i = 0; i < 4; ++i) {
    const int ncol = n0 + wn * 64 + i * 16 + lrow;
#pragma unroll
    for (int j = 0; j < 4; ++j) {
      const int mloc = wm * 64 + j * 16 + lcol;
      if (m0 + mloc < cnt)
        *(f32x4*)(obuf + (size_t)(base_row + mloc) * kH + ncol) = acc[i][j];
    }
  }
}

// ---------------- kernel 5: combine obuf slots -> out ----------------
// grid (kH/1024, kT), 256 threads; each thread one float4.
__global__ void combine_kernel(const float* __restrict__ obuf,
                               const int* __restrict__ pos,
                               const int* __restrict__ offs,
                               float* __restrict__ out) {
  const int t   = blockIdx.y;
  const int col = blockIdx.x * 1024 + threadIdx.x * 4;
  const int c0  = pos[t * 2 + 0];
  const int c1  = pos[t * 2 + 1];
  const int row0 = offs[c0 >> 12] + (c0 & 4095);
  float4 v = *(const float4*)(obuf + (size_t)row0 * kH + col);
  if (c1 >= 0) {
    const int row1 = offs[c1 >> 12] + (c1 & 4095);
    float4 w = *(const float4*)(obuf + (size_t)row1 * kH + col);
    v.x += w.x; v.y += w.y; v.z += w.z; v.w += w.w;
  }
  *(float4*)(out + (size_t)t * kH + col) = v;
}

// ---------------- launcher ----------------
extern "C" void kernel_launch(void* const* d_in, const int* in_sizes, int n_in,
                              void* d_out, int out_size, void* d_ws, size_t ws_size,
                              hipStream_t stream) {
  const float* hs   = (const float*)d_in[0];
  const float* aff  = (const float*)d_in[1];
  const int*   eidx = (const int*)d_in[2];
  const float* wg   = (const float*)d_in[3];
  const float* wu   = (const float*)d_in[4];
  const float* wd   = (const float*)d_in[5];
  float* out = (float*)d_out;

  char* ws = (char*)d_ws;
  unsigned short* hsb  = (unsigned short*)(ws + HSB_OFF);
  unsigned short* hbuf = (unsigned short*)(ws + HBUF_OFF);
  int*            cnts = (int*)(ws + CNT_OFF);
  int*            offs = (int*)(ws + OFF_OFF);
  int*            ltok = (int*)(ws + LTOK_OFF);
  float*          lwgt = (float*)(ws + LW_OFF);
  int*            pos  = (int*)(ws + POS_OFF);
  unsigned short* wgT  = (unsigned short*)(ws + WGT_OFF);
  unsigned short* wuT  = (unsigned short*)(ws + WUT_OFF);
  unsigned short* wdT  = (unsigned short*)(ws + WDT_OFF);
  float*          obuf = (float*)(ws + WGT_OFF);   // aliases wgT (dead by then)

  hipMemsetAsync(cnts, 0, kE * sizeof(int), stream);

  cvt_hs_kernel<<<(kT * kH) / (256 * 8), 256, 0, stream>>>(hs, hsb);
  route_kernel<<<kT / 256, 256, 0, stream>>>(aff, eidx, cnts, ltok, lwgt, pos);
  prefix_kernel<<<1, 64, 0, stream>>>(cnts, offs);

  tcvt_kernel<<<dim3(kI / 64, kH / 64, kE), 256, 0, stream>>>(wg, wgT, kH, kI);
  tcvt_kernel<<<dim3(kI / 64, kH / 64, kE), 256, 0, stream>>>(wu, wuT, kH, kI);
  tcvt_kernel<<<dim3(kH / 64, kI / 64, kE), 256, 0, stream>>>(wd, wdT, kI, kH);

  gemm_gu_kernel<<<dim3(kI / 128, kCap / 128, kE), 256, 0, stream>>>(
      hsb, wgT, wuT, cnts, offs, ltok, lwgt, hbuf);
  gemm_dn_kernel<<<dim3(kH / 128, kCap / 128, kE), 256, 0, stream>>>(
      hbuf, wdT, cnts, offs, obuf);
  combine_kernel<<<dim3(kH / 1024, kT), 256, 0, stream>>>(obuf, pos, offs, out);
}